// Round 16
// baseline (365.815 us; speedup 1.0000x reference)
//
#include <hip/hip_runtime.h>

#define NB  64
#define IC  2048
#define ID  16
#define DD  256
#define DDSQ 65536
#define PB  (DDSQ * NB)       // 4,194,304 floats = one full-batch fp32-sized buffer
#define NSQ 11                // matrix squarings
#define NPI 7                 // finish matvecs: exponent 2^11 * 8 = 16384

typedef __attribute__((ext_vector_type(8))) short          s16x8;  // 8 bf16 (4 VGPRs) MFMA frag
typedef __attribute__((ext_vector_type(4))) float          f32x4;  // MFMA acc
typedef __attribute__((ext_vector_type(4))) unsigned short us4;
typedef __attribute__((ext_vector_type(8))) unsigned short us8;

// fp32 -> bf16 (RNE) and back, via raw bits
__device__ __forceinline__ unsigned short f2b(float f) {
    union { float f; unsigned u; } c; c.f = f;
    const unsigned u = c.u + 0x7FFFu + ((c.u >> 16) & 1u);
    return (unsigned short)(u >> 16);
}
__device__ __forceinline__ float b2f(unsigned short h) {
    union { unsigned u; float f; } c; c.u = ((unsigned)h) << 16;
    return c.f;
}
// fp32 -> packed (hi bf16 << 16) | (lo bf16): 2-term split in one u32
__device__ __forceinline__ unsigned f2pk(float f) {
    const unsigned short h = f2b(f);
    const unsigned short l = f2b(f - b2f(h));
    return ((unsigned)h << 16) | (unsigned)l;
}
// upper-triangle tile enumeration (uniform scalar branch chain, rule #20 safe)
__device__ __forceinline__ void tri_map(int tile, int& tr, int& tc) {
    if (tile < 4)      { tr = 0; tc = tile; }
    else if (tile < 7) { tr = 1; tc = tile - 3; }
    else if (tile < 9) { tr = 2; tc = tile - 5; }
    else               { tr = 3; tc = 3; }
}

// ---------------- stage 1: u[b,c,:] = x[b,c,:] @ W_c (ALL 64 batches/block) -
// One block per capsule c (2048 blocks): W row read ONCE (round-10 proven).
__global__ __launch_bounds__(256, 4) void u_kernel(const float* __restrict__ caps,
                                                   const float* __restrict__ W,
                                                   unsigned* __restrict__ U) {
    const int c = blockIdx.x;
    const int t = threadIdx.x;
    __shared__ float xsT[ID][64];        // [dim][batch] (4 KB)
    {
        const int b = t >> 2, q = (t & 3) * 4;
        const float4 x4 = *(const float4*)&caps[((size_t)b * IC + c) * ID + q];
        xsT[q + 0][b] = x4.x; xsT[q + 1][b] = x4.y;
        xsT[q + 2][b] = x4.z; xsT[q + 3][b] = x4.w;
    }
    __syncthreads();
    float a[64];
#pragma unroll
    for (int b = 0; b < 64; ++b) a[b] = 0.f;
#pragma unroll
    for (int i = 0; i < ID; ++i) {
        const float wi = W[((size_t)c * ID + i) * DD + t];    // coalesced over t
#pragma unroll
        for (int g = 0; g < 16; ++g) {
            const float4 x = *(const float4*)&xsT[i][g * 4];
            a[g * 4 + 0] = fmaf(x.x, wi, a[g * 4 + 0]);
            a[g * 4 + 1] = fmaf(x.y, wi, a[g * 4 + 1]);
            a[g * 4 + 2] = fmaf(x.z, wi, a[g * 4 + 2]);
            a[g * 4 + 3] = fmaf(x.w, wi, a[g * 4 + 3]);
        }
    }
#pragma unroll
    for (int b = 0; b < 64; ++b)
        U[((size_t)b * IC + c) * DD + t] = f2pk(a[b]);
}

// ---- stage 2: C = U^T U, SPLIT-K, 64x64 tri tiles, 1280 blocks -------------
// Occupancy fix for the R15 diagnosis (2.5 blocks/CU, latency-bound): 2 k-
// chunks x 640 tri-tiles = 1280 blocks (5/CU). Both chunks atomicAdd fp32
// into folded F (device-scope per m20; exactly 2 commutative IEEE adds per
// element => deterministic). Body = R14 cm64 (proven) with k-range param.
__global__ __launch_bounds__(256, 4)
void cm64sk_kernel(const unsigned* __restrict__ Up,
                   float* __restrict__ F, float* __restrict__ Sc) {
    const int id   = blockIdx.x;          // 1280 = 64 batches x 10 tiles x 2 kch
    const int bb   = id & 63;
    const int tk   = id >> 6;             // 0..19
    const int tile = tk >> 1, kch = tk & 1;
    int tr, tc; tri_map(tile, tr, tc);
    const int d0 = tr * 64, e0 = tc * 64;
    const int t    = threadIdx.x;
    const int lane = t & 63, wid = t >> 6;
    const int wm = wid >> 1, wn = wid & 1;            // 2x2 wave grid, 32x32/wave
    const int fr = lane & 15, kg = lane >> 4;         // frag row, k-group
    const int sl8 = lane & 7, qg = lane >> 3;         // staging: row-in-octet, k-quad
    const size_t mb = (size_t)bb * DDSQ;

    __shared__ unsigned short Ah[64][40];   // [d][k], pitch 40 shorts (80 B)
    __shared__ unsigned short Al[64][40];
    __shared__ unsigned short Bh[64][40];   // [e][k]
    __shared__ unsigned short Bl[64][40];
    __shared__ float red[256];

    const f32x4 z4 = {0.f, 0.f, 0.f, 0.f};
    f32x4 acc[2][2];
#pragma unroll
    for (int m = 0; m < 2; ++m)
#pragma unroll
        for (int n = 0; n < 2; ++n) acc[m][n] = z4;

    const unsigned* Ub = Up + (size_t)bb * IC * DD;
    const int k0 = kch * (IC / 2);
    unsigned va[2][4], vb[2][4];
    auto loadU = [&](int kb) {
#pragma unroll
        for (int s = 0; s < 2; ++s) {
            const int row = wid * 8 + sl8 + 32 * s;       // d-local 0..63
#pragma unroll
            for (int j = 0; j < 4; ++j)
                va[s][j] = Ub[(size_t)(kb + 4 * qg + j) * DD + d0 + row];
        }
#pragma unroll
        for (int s = 0; s < 2; ++s) {
            const int row = wid * 8 + sl8 + 32 * s;       // e-local 0..63
#pragma unroll
            for (int j = 0; j < 4; ++j)
                vb[s][j] = Ub[(size_t)(kb + 4 * qg + j) * DD + e0 + row];
        }
    };

    loadU(k0);
    for (int kb = k0; kb < k0 + IC / 2; kb += 32) {
        __syncthreads();
#pragma unroll
        for (int s = 0; s < 2; ++s) {
            const int row = wid * 8 + sl8 + 32 * s;
            us4 h, l;
#pragma unroll
            for (int j = 0; j < 4; ++j) {
                h[j] = (unsigned short)(va[s][j] >> 16);
                l[j] = (unsigned short)(va[s][j] & 0xFFFFu);
            }
            *(us4*)&Ah[row][4 * qg] = h;
            *(us4*)&Al[row][4 * qg] = l;
        }
#pragma unroll
        for (int s = 0; s < 2; ++s) {
            const int row = wid * 8 + sl8 + 32 * s;
            us4 h, l;
#pragma unroll
            for (int j = 0; j < 4; ++j) {
                h[j] = (unsigned short)(vb[s][j] >> 16);
                l[j] = (unsigned short)(vb[s][j] & 0xFFFFu);
            }
            *(us4*)&Bh[row][4 * qg] = h;
            *(us4*)&Bl[row][4 * qg] = l;
        }
        __syncthreads();
        if (kb + 32 < k0 + IC / 2) loadU(kb + 32);   // T14 prefetch
        s16x8 ah[2], al[2], bh[2], bl[2];
#pragma unroll
        for (int m = 0; m < 2; ++m) {
            const int r = wm * 32 + m * 16 + fr;
            ah[m] = *(const s16x8*)&Ah[r][kg * 8];
            al[m] = *(const s16x8*)&Al[r][kg * 8];
        }
#pragma unroll
        for (int n = 0; n < 2; ++n) {
            const int r = wn * 32 + n * 16 + fr;
            bh[n] = *(const s16x8*)&Bh[r][kg * 8];
            bl[n] = *(const s16x8*)&Bl[r][kg * 8];
        }
#pragma unroll
        for (int m = 0; m < 2; ++m)
#pragma unroll
            for (int n = 0; n < 2; ++n) {
                acc[m][n] = __builtin_amdgcn_mfma_f32_16x16x32_bf16(ah[m], bh[n], acc[m][n], 0, 0, 0);
                acc[m][n] = __builtin_amdgcn_mfma_f32_16x16x32_bf16(ah[m], bl[n], acc[m][n], 0, 0, 0);
                acc[m][n] = __builtin_amdgcn_mfma_f32_16x16x32_bf16(al[m], bh[n], acc[m][n], 0, 0, 0);
            }
    }

    // epilogue: fp32 atomic fold into F (+ mirror) + partial trace
    float* Fb = F + mb;
    float ts = 0.f;
    const int row_l = wm * 32 + (lane >> 4) * 4;
    const int col_l = wn * 32 + fr;
    const bool mir = (tr != tc);
#pragma unroll
    for (int m = 0; m < 2; ++m)
#pragma unroll
        for (int n = 0; n < 2; ++n) {
            const int gr0 = d0 + row_l + m * 16;
            const int gc  = e0 + col_l + n * 16;
#pragma unroll
            for (int r = 0; r < 4; ++r) {
                const float e = acc[m][n][r];
                atomicAdd(&Fb[(size_t)(gr0 + r) * DD + gc], e);
                if (mir) atomicAdd(&Fb[(size_t)gc * DD + gr0 + r], e);
                if (gr0 + r == gc) ts += e;
            }
        }
    if (tr == tc) {                       // 4 diag tiles x 2 chunks -> 8 adds
        red[t] = ts;
        __syncthreads();
        for (int s2 = 128; s2 > 0; s2 >>= 1) {
            if (t < s2) red[t] += red[t + s2];
            __syncthreads();
        }
        if (t == 0) atomicAdd(&Sc[bb], red[0]);
    }
}

// ---- squaring #1: E = (F/s)^2, fp32 input, 64x64 tri, BK=32 ----------------
// R2's proven FIRST staging (fp32 -> hi/lo split in LDS; identical rounding
// points to the stored-bf16 path) x both panels + R10 MFMA body + R12
// tri/mirror epilogue. 640 blocks.
__global__ __launch_bounds__(256, 4)
void sqf_kernel(const float* __restrict__ F,
                unsigned short* __restrict__ Eh, unsigned short* __restrict__ El,
                const float* __restrict__ s_in, float* __restrict__ s_out) {
    const int id   = blockIdx.x;          // 640 = 64 batches x 10 tri-tiles
    const int bb   = id & 63;
    const int tile = id >> 6;
    int tr, tc; tri_map(tile, tr, tc);
    const int d0 = tr * 64, e0 = tc * 64;
    const int t    = threadIdx.x;
    const int lane = t & 63, wid = t >> 6;
    const int wm = wid >> 1, wn = wid & 1;
    const int fr = lane & 15, kg = lane >> 4;
    const size_t mb = (size_t)bb * DDSQ;

    __shared__ unsigned short Ah[64][40];
    __shared__ unsigned short Al[64][40];
    __shared__ unsigned short Bh[64][40];
    __shared__ unsigned short Bl[64][40];
    __shared__ float red[256];

    const f32x4 z4 = {0.f, 0.f, 0.f, 0.f};
    f32x4 acc[2][2];
#pragma unroll
    for (int m = 0; m < 2; ++m)
#pragma unroll
        for (int n = 0; n < 2; ++n) acc[m][n] = z4;

    const float s   = s_in[bb];
    const float inv = 1.f / (s * s);

    for (int kb = 0; kb < DD; kb += 32) {
        // fp32 staging: 512 slots, row=slot>>3, q8=slot&7 (R2 FIRST geometry)
        float4 va[2], vb[2];
#pragma unroll
        for (int i = 0; i < 2; ++i) {
            const int slot = t + i * 256;
            const int row = slot >> 3, q8 = slot & 7;
            va[i] = *(const float4*)&F[mb + (size_t)(d0 + row) * DD + kb + q8 * 4];
            vb[i] = *(const float4*)&F[mb + (size_t)(e0 + row) * DD + kb + q8 * 4];
        }
        __syncthreads();
#pragma unroll
        for (int i = 0; i < 2; ++i) {
            const int slot = t + i * 256;
            const int row = slot >> 3, q8 = slot & 7;
            us4 h, l;
            h.x = f2b(va[i].x); l.x = f2b(va[i].x - b2f(h.x));
            h.y = f2b(va[i].y); l.y = f2b(va[i].y - b2f(h.y));
            h.z = f2b(va[i].z); l.z = f2b(va[i].z - b2f(h.z));
            h.w = f2b(va[i].w); l.w = f2b(va[i].w - b2f(h.w));
            *(us4*)&Ah[row][q8 * 4] = h;
            *(us4*)&Al[row][q8 * 4] = l;
            h.x = f2b(vb[i].x); l.x = f2b(vb[i].x - b2f(h.x));
            h.y = f2b(vb[i].y); l.y = f2b(vb[i].y - b2f(h.y));
            h.z = f2b(vb[i].z); l.z = f2b(vb[i].z - b2f(h.z));
            h.w = f2b(vb[i].w); l.w = f2b(vb[i].w - b2f(h.w));
            *(us4*)&Bh[row][q8 * 4] = h;
            *(us4*)&Bl[row][q8 * 4] = l;
        }
        __syncthreads();

        s16x8 ah[2], al[2], bh[2], bl[2];
#pragma unroll
        for (int m = 0; m < 2; ++m) {
            const int r = wm * 32 + m * 16 + fr;
            ah[m] = *(const s16x8*)&Ah[r][kg * 8];
            al[m] = *(const s16x8*)&Al[r][kg * 8];
        }
#pragma unroll
        for (int n = 0; n < 2; ++n) {
            const int r = wn * 32 + n * 16 + fr;
            bh[n] = *(const s16x8*)&Bh[r][kg * 8];
            bl[n] = *(const s16x8*)&Bl[r][kg * 8];
        }
#pragma unroll
        for (int m = 0; m < 2; ++m)
#pragma unroll
            for (int n = 0; n < 2; ++n) {
                acc[m][n] = __builtin_amdgcn_mfma_f32_16x16x32_bf16(ah[m], bh[n], acc[m][n], 0, 0, 0);
                acc[m][n] = __builtin_amdgcn_mfma_f32_16x16x32_bf16(ah[m], bl[n], acc[m][n], 0, 0, 0);
                acc[m][n] = __builtin_amdgcn_mfma_f32_16x16x32_bf16(al[m], bh[n], acc[m][n], 0, 0, 0);
            }
    }

    // epilogue: scale, trace, split to hi/lo bf16; mirror off-diag tiles
    float ts = 0.f;
    const int row_l = wm * 32 + (lane >> 4) * 4;
    const int col_l = wn * 32 + fr;
    const bool mir = (tr != tc);
#pragma unroll
    for (int m = 0; m < 2; ++m)
#pragma unroll
        for (int n = 0; n < 2; ++n) {
            const int gr0 = d0 + row_l + m * 16;
            const int gc  = e0 + col_l + n * 16;
            us4 h4, l4;
#pragma unroll
            for (int r = 0; r < 4; ++r) {
                const float e = acc[m][n][r] * inv;
                const unsigned short h = f2b(e);
                const unsigned short l = f2b(e - b2f(h));
                const size_t o = mb + (size_t)(gr0 + r) * DD + gc;
                Eh[o] = h; El[o] = l;
                h4[r] = h; l4[r] = l;
                if (gr0 + r == gc) ts += e;
            }
            if (mir) {
                const size_t o2 = mb + (size_t)gc * DD + gr0;
                *(us4*)&Eh[o2] = h4;
                *(us4*)&El[o2] = l4;
            }
        }
    if (tr == tc) {
        red[t] = ts;
        __syncthreads();
        for (int s2 = 128; s2 > 0; s2 >>= 1) {
            if (t < s2) red[t] += red[t + s2];
            __syncthreads();
        }
        if (t == 0) atomicAdd(&s_out[bb], red[0]);
    }
}

// ---- E = (D/s)^2, 64x64 tile, BK=64, UPPER-TRIANGLE ONLY (640 blocks) ------
// EXACT round-12/14-proven body (bit-identical output).
__global__ __launch_bounds__(256, 4)
void sqm_kernel(const unsigned short* __restrict__ Dh, const unsigned short* __restrict__ Dl,
                unsigned short* __restrict__ Eh, unsigned short* __restrict__ El,
                const float* __restrict__ s_in, float* __restrict__ s_out) {
    const int id   = blockIdx.x;          // 640 = 64 batches x 10 tri-tiles
    const int bb   = id & 63;
    const int tile = id >> 6;
    int tr, tc; tri_map(tile, tr, tc);
    const int d0 = tr * 64, e0 = tc * 64;
    const int t    = threadIdx.x;
    const int lane = t & 63, wid = t >> 6;
    const int wm = wid >> 1, wn = wid & 1;
    const int fr = lane & 15, kg = lane >> 4;
    const size_t mb = (size_t)bb * DDSQ;

    __shared__ unsigned short Ah[64][72];   // pitch 72 shorts (144 B)
    __shared__ unsigned short Al[64][72];
    __shared__ unsigned short Bh[64][72];
    __shared__ unsigned short Bl[64][72];
    __shared__ float red[256];

    const f32x4 z4 = {0.f, 0.f, 0.f, 0.f};
    f32x4 acc[2][2];
#pragma unroll
    for (int m = 0; m < 2; ++m)
#pragma unroll
        for (int n = 0; n < 2; ++n) acc[m][n] = z4;

    const float s   = s_in[bb];
    const float inv = 1.f / (s * s);
    const int row = t >> 2, q = t & 3;    // staging map: 64 rows x 4 k-quads

    for (int kb = 0; kb < DD; kb += 64) {
        const size_t ga = mb + (size_t)(d0 + row) * DD + kb + q * 8;
        const size_t gb = mb + (size_t)(e0 + row) * DD + kb + q * 8;
        const int4 rah0 = *(const int4*)&Dh[ga];
        const int4 rah1 = *(const int4*)&Dh[ga + 32];
        const int4 ral0 = *(const int4*)&Dl[ga];
        const int4 ral1 = *(const int4*)&Dl[ga + 32];
        const int4 rbh0 = *(const int4*)&Dh[gb];
        const int4 rbh1 = *(const int4*)&Dh[gb + 32];
        const int4 rbl0 = *(const int4*)&Dl[gb];
        const int4 rbl1 = *(const int4*)&Dl[gb + 32];
        __syncthreads();
        *(int4*)&Ah[row][q * 8]      = rah0;
        *(int4*)&Ah[row][q * 8 + 32] = rah1;
        *(int4*)&Al[row][q * 8]      = ral0;
        *(int4*)&Al[row][q * 8 + 32] = ral1;
        *(int4*)&Bh[row][q * 8]      = rbh0;
        *(int4*)&Bh[row][q * 8 + 32] = rbh1;
        *(int4*)&Bl[row][q * 8]      = rbl0;
        *(int4*)&Bl[row][q * 8 + 32] = rbl1;
        __syncthreads();

#pragma unroll
        for (int h = 0; h < 2; ++h) {
            const int ko = kg * 8 + 32 * h;
            s16x8 ah[2], al[2], bh[2], bl[2];
#pragma unroll
            for (int m = 0; m < 2; ++m) {
                const int r = wm * 32 + m * 16 + fr;
                ah[m] = *(const s16x8*)&Ah[r][ko];
                al[m] = *(const s16x8*)&Al[r][ko];
            }
#pragma unroll
            for (int n = 0; n < 2; ++n) {
                const int r = wn * 32 + n * 16 + fr;
                bh[n] = *(const s16x8*)&Bh[r][ko];
                bl[n] = *(const s16x8*)&Bl[r][ko];
            }
#pragma unroll
            for (int m = 0; m < 2; ++m)
#pragma unroll
                for (int n = 0; n < 2; ++n) {
                    acc[m][n] = __builtin_amdgcn_mfma_f32_16x16x32_bf16(ah[m], bh[n], acc[m][n], 0, 0, 0);
                    acc[m][n] = __builtin_amdgcn_mfma_f32_16x16x32_bf16(ah[m], bl[n], acc[m][n], 0, 0, 0);
                    acc[m][n] = __builtin_amdgcn_mfma_f32_16x16x32_bf16(al[m], bh[n], acc[m][n], 0, 0, 0);
                }
        }
    }

    // epilogue: scale, trace, split to hi/lo bf16; mirror off-diag tiles
    float ts = 0.f;
    const int row_l = wm * 32 + (lane >> 4) * 4;
    const int col_l = wn * 32 + fr;
    const bool mir = (tr != tc);
#pragma unroll
    for (int m = 0; m < 2; ++m)
#pragma unroll
        for (int n = 0; n < 2; ++n) {
            const int gr0 = d0 + row_l + m * 16;
            const int gc  = e0 + col_l + n * 16;
            us4 h4, l4;
#pragma unroll
            for (int r = 0; r < 4; ++r) {
                const float e = acc[m][n][r] * inv;
                const unsigned short h = f2b(e);
                const unsigned short l = f2b(e - b2f(h));
                const size_t o = mb + (size_t)(gr0 + r) * DD + gc;
                Eh[o] = h; El[o] = l;
                h4[r] = h; l4[r] = l;
                if (gr0 + r == gc) ts += e;
            }
            if (mir) {
                const size_t o2 = mb + (size_t)gc * DD + gr0;
                *(us4*)&Eh[o2] = h4;
                *(us4*)&El[o2] = l4;
            }
        }
    if (tr == tc) {
        red[t] = ts;
        __syncthreads();
        for (int s2 = 128; s2 > 0; s2 >>= 1) {
            if (t < s2) red[t] += red[t + s2];
            __syncthreads();
        }
        if (t == 0) atomicAdd(&s_out[bb], red[0]);
    }
}

// ------- finish: 1024 threads/block (round-15 proven) -----------------------
__global__ __launch_bounds__(1024, 1)
void finish_kernel(const unsigned short* __restrict__ Dh,
                   const unsigned short* __restrict__ Dl,
                   float* __restrict__ out) {
    const int b = blockIdx.x, t = threadIdx.x;
    const int row = t >> 2, q = t & 3;
    const size_t mb = (size_t)b * DDSQ;
    __shared__ float vs[DD];
    __shared__ float red[DD];
    __shared__ int   ridx[DD];
    if (t < DD) {
        red[t] = b2f(Dh[mb + (size_t)t * DD + t]) + b2f(Dl[mb + (size_t)t * DD + t]);
        ridx[t] = t;
    }
    __syncthreads();
    for (int s = 128; s > 0; s >>= 1) {
        if (t < s && red[t + s] > red[t]) { red[t] = red[t + s]; ridx[t] = ridx[t + s]; }
        __syncthreads();
    }
    const int jmax0 = ridx[0];
    __syncthreads();
    if (t < DD)
        vs[t] = b2f(Dh[mb + (size_t)jmax0 * DD + t]) + b2f(Dl[mb + (size_t)jmax0 * DD + t]);
    __syncthreads();

    const unsigned short* rh = Dh + mb + (size_t)row * DD + q * 64;
    const unsigned short* rl = Dl + mb + (size_t)row * DD + q * 64;
    for (int it = 0; it < NPI; ++it) {
        float a = 0.f;
        const float* vq = vs + q * 64;
#pragma unroll
        for (int j = 0; j < 64; j += 8) {
            const us8 h8 = *(const us8*)&rh[j];
            const us8 l8 = *(const us8*)&rl[j];
            a = fmaf(b2f(h8[0]) + b2f(l8[0]), vq[j + 0], a);
            a = fmaf(b2f(h8[1]) + b2f(l8[1]), vq[j + 1], a);
            a = fmaf(b2f(h8[2]) + b2f(l8[2]), vq[j + 2], a);
            a = fmaf(b2f(h8[3]) + b2f(l8[3]), vq[j + 3], a);
            a = fmaf(b2f(h8[4]) + b2f(l8[4]), vq[j + 4], a);
            a = fmaf(b2f(h8[5]) + b2f(l8[5]), vq[j + 5], a);
            a = fmaf(b2f(h8[6]) + b2f(l8[6]), vq[j + 6], a);
            a = fmaf(b2f(h8[7]) + b2f(l8[7]), vq[j + 7], a);
        }
        a += __shfl_xor(a, 1);
        a += __shfl_xor(a, 2);
        __syncthreads();
        if (q == 0) vs[row] = a;
        __syncthreads();
    }

    if (t < DD) red[t] = vs[t] * vs[t];
    __syncthreads();
    for (int s = 128; s > 0; s >>= 1) {
        if (t < s) red[t] += red[t + s];
        __syncthreads();
    }
    const float nrm = sqrtf(red[0]);
    __syncthreads();
    if (t < DD) { red[t] = fabsf(vs[t]); ridx[t] = t; }
    __syncthreads();
    for (int s = 128; s > 0; s >>= 1) {
        if (t < s && red[t + s] > red[t]) { red[t] = red[t + s]; ridx[t] = ridx[t + s]; }
        __syncthreads();
    }
    const float sgn = (vs[ridx[0]] < 0.f) ? -1.f : 1.f;
    if (t < DD) out[(size_t)b * DD + t] = sgn * vs[t] / nrm;
}

extern "C" void kernel_launch(void* const* d_in, const int* in_sizes, int n_in,
                              void* d_out, int out_size, void* d_ws, size_t ws_size,
                              hipStream_t stream) {
    const float* caps = (const float*)d_in[0];   // (64, 2048, 16)
    const float* W    = (const float*)d_in[1];   // (2048, 16, 256)
    float* out = (float*)d_out;                  // (64, 256)
    float* ws  = (float*)d_ws;

    // layout: Up packed = 8*PB @0 | F fp32 @8PB (16.8 MB) | B0 @9PB | Sc @10PB
    // After sqf, F is dead -> B1 (chain pong) overlays F's region. 168 MB total.
    unsigned* Up = (unsigned*)ws;
    float* F = ws + (size_t)8 * PB;
    unsigned short* B0h = (unsigned short*)(ws + (size_t)9 * PB);
    unsigned short* B0l = B0h + (size_t)NB * DDSQ;
    unsigned short* B1h = (unsigned short*)(ws + (size_t)8 * PB);
    unsigned short* B1l = B1h + (size_t)NB * DDSQ;
    float* Sc = ws + (size_t)10 * PB;

    hipMemsetAsync(Sc, 0, 2048 * sizeof(float), stream);
    hipMemsetAsync(F, 0, (size_t)PB * sizeof(float), stream);   // atomic fold target

    u_kernel<<<IC, 256, 0, stream>>>(caps, W, Up);
    cm64sk_kernel<<<1280, 256, 0, stream>>>(Up, F, Sc);        // C (fp32, folded)

    // squaring #1: fp32 F -> bf16 pair B0 (also frees F's region for the chain)
    sqf_kernel<<<640, 256, 0, stream>>>(F, B0h, B0l, Sc, Sc + 64);

    unsigned short* ph = B0h; unsigned short* pl = B0l;
    unsigned short* qh = B1h; unsigned short* ql = B1l;
    for (int it = 1; it < NSQ; ++it) {
        sqm_kernel<<<640, 256, 0, stream>>>(ph, pl, qh, ql,
                                            Sc + it * 64, Sc + (it + 1) * 64);
        unsigned short* t1 = ph; ph = qh; qh = t1;
        unsigned short* t2 = pl; pl = ql; ql = t2;
    }

    finish_kernel<<<NB, 1024, 0, stream>>>(ph, pl, out);   // 10 swaps -> B0
}

// Round 17
// 335.514 us; speedup vs baseline: 1.0903x; 1.0903x over previous
//
#include <hip/hip_runtime.h>

#define NB  64
#define IC  2048
#define ID  16
#define DD  256
#define DDSQ 65536
#define PB  (DDSQ * NB)       // 4,194,304 floats = one full-batch fp32-sized buffer
#define NSQ 11                // matrix squarings
#define NPI 7                 // finish matvecs: exponent 2^11 * 8 = 16384

typedef __attribute__((ext_vector_type(8))) short          s16x8;  // 8 bf16 (4 VGPRs) MFMA frag
typedef __attribute__((ext_vector_type(4))) float          f32x4;  // MFMA acc
typedef __attribute__((ext_vector_type(4))) unsigned short us4;
typedef __attribute__((ext_vector_type(8))) unsigned short us8;

#define ADDF4(a, b) { (a).x += (b).x; (a).y += (b).y; (a).z += (b).z; (a).w += (b).w; }

// fp32 -> bf16 (RNE) and back, via raw bits
__device__ __forceinline__ unsigned short f2b(float f) {
    union { float f; unsigned u; } c; c.f = f;
    const unsigned u = c.u + 0x7FFFu + ((c.u >> 16) & 1u);
    return (unsigned short)(u >> 16);
}
__device__ __forceinline__ float b2f(unsigned short h) {
    union { unsigned u; float f; } c; c.u = ((unsigned)h) << 16;
    return c.f;
}
// fp32 -> packed (hi bf16 << 16) | (lo bf16): 2-term split in one u32
__device__ __forceinline__ unsigned f2pk(float f) {
    const unsigned short h = f2b(f);
    const unsigned short l = f2b(f - b2f(h));
    return ((unsigned)h << 16) | (unsigned)l;
}
// upper-triangle tile enumeration (uniform scalar branch chain, rule #20 safe)
__device__ __forceinline__ void tri_map(int tile, int& tr, int& tc) {
    if (tile < 4)      { tr = 0; tc = tile; }
    else if (tile < 7) { tr = 1; tc = tile - 3; }
    else if (tile < 9) { tr = 2; tc = tile - 5; }
    else               { tr = 3; tc = 3; }
}

// ---------------- stage 1: u[b,c,:] = x[b,c,:] @ W_c (ALL 64 batches/block) -
// One block per capsule c (2048 blocks): W row read ONCE (round-10 proven).
__global__ __launch_bounds__(256, 4) void u_kernel(const float* __restrict__ caps,
                                                   const float* __restrict__ W,
                                                   unsigned* __restrict__ U) {
    const int c = blockIdx.x;
    const int t = threadIdx.x;
    __shared__ float xsT[ID][64];        // [dim][batch] (4 KB)
    {
        const int b = t >> 2, q = (t & 3) * 4;
        const float4 x4 = *(const float4*)&caps[((size_t)b * IC + c) * ID + q];
        xsT[q + 0][b] = x4.x; xsT[q + 1][b] = x4.y;
        xsT[q + 2][b] = x4.z; xsT[q + 3][b] = x4.w;
    }
    __syncthreads();
    float a[64];
#pragma unroll
    for (int b = 0; b < 64; ++b) a[b] = 0.f;
#pragma unroll
    for (int i = 0; i < ID; ++i) {
        const float wi = W[((size_t)c * ID + i) * DD + t];    // coalesced over t
#pragma unroll
        for (int g = 0; g < 16; ++g) {
            const float4 x = *(const float4*)&xsT[i][g * 4];
            a[g * 4 + 0] = fmaf(x.x, wi, a[g * 4 + 0]);
            a[g * 4 + 1] = fmaf(x.y, wi, a[g * 4 + 1]);
            a[g * 4 + 2] = fmaf(x.z, wi, a[g * 4 + 2]);
            a[g * 4 + 3] = fmaf(x.w, wi, a[g * 4 + 3]);
        }
    }
#pragma unroll
    for (int b = 0; b < 64; ++b)
        U[((size_t)b * IC + c) * DD + t] = f2pk(a[b]);
}

// ---- stage 2: C = U^T U, SPLIT-K (no atomics), 64x64 tri tiles, 1280 blk ---
// R16 post-mortem: occupancy gain (36%) was real, atomic fold traffic killed
// it (WRITE 17->70 MB). Fix = R2's proven P0/P1 pattern: each k-half PLAIN-
// stores its fp32 partial (+R14-proven float4 transposed mirror) to its own
// buffer; sqf folds F0+F1 (2 commutative IEEE adds => deterministic).
__global__ __launch_bounds__(256, 4)
void cm64sk_kernel(const unsigned* __restrict__ Up,
                   float* __restrict__ F0, float* __restrict__ F1,
                   float* __restrict__ Sc) {
    const int id   = blockIdx.x;          // 1280 = 64 batches x 10 tiles x 2 kch
    const int bb   = id & 63;
    const int tk   = id >> 6;             // 0..19
    const int tile = tk >> 1, kch = tk & 1;
    int tr, tc; tri_map(tile, tr, tc);
    const int d0 = tr * 64, e0 = tc * 64;
    const int t    = threadIdx.x;
    const int lane = t & 63, wid = t >> 6;
    const int wm = wid >> 1, wn = wid & 1;            // 2x2 wave grid, 32x32/wave
    const int fr = lane & 15, kg = lane >> 4;         // frag row, k-group
    const int sl8 = lane & 7, qg = lane >> 3;         // staging: row-in-octet, k-quad
    const size_t mb = (size_t)bb * DDSQ;

    __shared__ unsigned short Ah[64][40];   // [d][k], pitch 40 shorts (80 B)
    __shared__ unsigned short Al[64][40];
    __shared__ unsigned short Bh[64][40];   // [e][k]
    __shared__ unsigned short Bl[64][40];
    __shared__ float red[256];

    const f32x4 z4 = {0.f, 0.f, 0.f, 0.f};
    f32x4 acc[2][2];
#pragma unroll
    for (int m = 0; m < 2; ++m)
#pragma unroll
        for (int n = 0; n < 2; ++n) acc[m][n] = z4;

    const unsigned* Ub = Up + (size_t)bb * IC * DD;
    const int k0 = kch * (IC / 2);
    unsigned va[2][4], vb[2][4];
    auto loadU = [&](int kb) {
#pragma unroll
        for (int s = 0; s < 2; ++s) {
            const int row = wid * 8 + sl8 + 32 * s;       // d-local 0..63
#pragma unroll
            for (int j = 0; j < 4; ++j)
                va[s][j] = Ub[(size_t)(kb + 4 * qg + j) * DD + d0 + row];
        }
#pragma unroll
        for (int s = 0; s < 2; ++s) {
            const int row = wid * 8 + sl8 + 32 * s;       // e-local 0..63
#pragma unroll
            for (int j = 0; j < 4; ++j)
                vb[s][j] = Ub[(size_t)(kb + 4 * qg + j) * DD + e0 + row];
        }
    };

    loadU(k0);
    for (int kb = k0; kb < k0 + IC / 2; kb += 32) {
        __syncthreads();
#pragma unroll
        for (int s = 0; s < 2; ++s) {
            const int row = wid * 8 + sl8 + 32 * s;
            us4 h, l;
#pragma unroll
            for (int j = 0; j < 4; ++j) {
                h[j] = (unsigned short)(va[s][j] >> 16);
                l[j] = (unsigned short)(va[s][j] & 0xFFFFu);
            }
            *(us4*)&Ah[row][4 * qg] = h;
            *(us4*)&Al[row][4 * qg] = l;
        }
#pragma unroll
        for (int s = 0; s < 2; ++s) {
            const int row = wid * 8 + sl8 + 32 * s;
            us4 h, l;
#pragma unroll
            for (int j = 0; j < 4; ++j) {
                h[j] = (unsigned short)(vb[s][j] >> 16);
                l[j] = (unsigned short)(vb[s][j] & 0xFFFFu);
            }
            *(us4*)&Bh[row][4 * qg] = h;
            *(us4*)&Bl[row][4 * qg] = l;
        }
        __syncthreads();
        if (kb + 32 < k0 + IC / 2) loadU(kb + 32);   // T14 prefetch
        s16x8 ah[2], al[2], bh[2], bl[2];
#pragma unroll
        for (int m = 0; m < 2; ++m) {
            const int r = wm * 32 + m * 16 + fr;
            ah[m] = *(const s16x8*)&Ah[r][kg * 8];
            al[m] = *(const s16x8*)&Al[r][kg * 8];
        }
#pragma unroll
        for (int n = 0; n < 2; ++n) {
            const int r = wn * 32 + n * 16 + fr;
            bh[n] = *(const s16x8*)&Bh[r][kg * 8];
            bl[n] = *(const s16x8*)&Bl[r][kg * 8];
        }
#pragma unroll
        for (int m = 0; m < 2; ++m)
#pragma unroll
            for (int n = 0; n < 2; ++n) {
                acc[m][n] = __builtin_amdgcn_mfma_f32_16x16x32_bf16(ah[m], bh[n], acc[m][n], 0, 0, 0);
                acc[m][n] = __builtin_amdgcn_mfma_f32_16x16x32_bf16(ah[m], bl[n], acc[m][n], 0, 0, 0);
                acc[m][n] = __builtin_amdgcn_mfma_f32_16x16x32_bf16(al[m], bh[n], acc[m][n], 0, 0, 0);
            }
    }

    // epilogue: PLAIN fp32 partial stores (+ float4 transposed mirror) + trace
    float* Fb = (kch ? F1 : F0) + mb;
    float ts = 0.f;
    const int row_l = wm * 32 + (lane >> 4) * 4;
    const int col_l = wn * 32 + fr;
    const bool mir = (tr != tc);
#pragma unroll
    for (int m = 0; m < 2; ++m)
#pragma unroll
        for (int n = 0; n < 2; ++n) {
            const int gr0 = d0 + row_l + m * 16;
            const int gc  = e0 + col_l + n * 16;
            float4 f4;
#pragma unroll
            for (int r = 0; r < 4; ++r) {
                const float e = acc[m][n][r];
                Fb[(size_t)(gr0 + r) * DD + gc] = e;
                ((float*)&f4)[r] = e;
                if (gr0 + r == gc) ts += e;
            }
            if (mir) {                    // transposed float4: row gc, cols gr0..+3
                *(float4*)&Fb[(size_t)gc * DD + gr0] = f4;
            }
        }
    if (tr == tc) {                       // 4 diag tiles x 2 chunks -> 8 adds
        red[t] = ts;
        __syncthreads();
        for (int s2 = 128; s2 > 0; s2 >>= 1) {
            if (t < s2) red[t] += red[t + s2];
            __syncthreads();
        }
        if (t == 0) atomicAdd(&Sc[bb], red[0]);
    }
}

// ---- squaring #1: E = ((F0+F1)/s)^2, fp32 fold-in-staging, 64x64 tri -------
// R2's proven ADD2+FIRST staging (fold then hi/lo split in LDS; identical
// rounding points to the atomic-folded path) + R10 MFMA body + R12 tri/mirror.
__global__ __launch_bounds__(256, 4)
void sqf_kernel(const float* __restrict__ F0, const float* __restrict__ F1,
                unsigned short* __restrict__ Eh, unsigned short* __restrict__ El,
                const float* __restrict__ s_in, float* __restrict__ s_out) {
    const int id   = blockIdx.x;          // 640 = 64 batches x 10 tri-tiles
    const int bb   = id & 63;
    const int tile = id >> 6;
    int tr, tc; tri_map(tile, tr, tc);
    const int d0 = tr * 64, e0 = tc * 64;
    const int t    = threadIdx.x;
    const int lane = t & 63, wid = t >> 6;
    const int wm = wid >> 1, wn = wid & 1;
    const int fr = lane & 15, kg = lane >> 4;
    const size_t mb = (size_t)bb * DDSQ;

    __shared__ unsigned short Ah[64][40];
    __shared__ unsigned short Al[64][40];
    __shared__ unsigned short Bh[64][40];
    __shared__ unsigned short Bl[64][40];
    __shared__ float red[256];

    const f32x4 z4 = {0.f, 0.f, 0.f, 0.f};
    f32x4 acc[2][2];
#pragma unroll
    for (int m = 0; m < 2; ++m)
#pragma unroll
        for (int n = 0; n < 2; ++n) acc[m][n] = z4;

    const float s   = s_in[bb];
    const float inv = 1.f / (s * s);

    for (int kb = 0; kb < DD; kb += 32) {
        // fp32 staging: 512 slots, row=slot>>3, q8=slot&7; fold F0+F1
        float4 va[2], vb[2];
#pragma unroll
        for (int i = 0; i < 2; ++i) {
            const int slot = t + i * 256;
            const int row = slot >> 3, q8 = slot & 7;
            const size_t ga = mb + (size_t)(d0 + row) * DD + kb + q8 * 4;
            const size_t gb = mb + (size_t)(e0 + row) * DD + kb + q8 * 4;
            va[i] = *(const float4*)&F0[ga];
            const float4 ya = *(const float4*)&F1[ga];
            ADDF4(va[i], ya);
            vb[i] = *(const float4*)&F0[gb];
            const float4 yb = *(const float4*)&F1[gb];
            ADDF4(vb[i], yb);
        }
        __syncthreads();
#pragma unroll
        for (int i = 0; i < 2; ++i) {
            const int slot = t + i * 256;
            const int row = slot >> 3, q8 = slot & 7;
            us4 h, l;
            h.x = f2b(va[i].x); l.x = f2b(va[i].x - b2f(h.x));
            h.y = f2b(va[i].y); l.y = f2b(va[i].y - b2f(h.y));
            h.z = f2b(va[i].z); l.z = f2b(va[i].z - b2f(h.z));
            h.w = f2b(va[i].w); l.w = f2b(va[i].w - b2f(h.w));
            *(us4*)&Ah[row][q8 * 4] = h;
            *(us4*)&Al[row][q8 * 4] = l;
            h.x = f2b(vb[i].x); l.x = f2b(vb[i].x - b2f(h.x));
            h.y = f2b(vb[i].y); l.y = f2b(vb[i].y - b2f(h.y));
            h.z = f2b(vb[i].z); l.z = f2b(vb[i].z - b2f(h.z));
            h.w = f2b(vb[i].w); l.w = f2b(vb[i].w - b2f(h.w));
            *(us4*)&Bh[row][q8 * 4] = h;
            *(us4*)&Bl[row][q8 * 4] = l;
        }
        __syncthreads();

        s16x8 ah[2], al[2], bh[2], bl[2];
#pragma unroll
        for (int m = 0; m < 2; ++m) {
            const int r = wm * 32 + m * 16 + fr;
            ah[m] = *(const s16x8*)&Ah[r][kg * 8];
            al[m] = *(const s16x8*)&Al[r][kg * 8];
        }
#pragma unroll
        for (int n = 0; n < 2; ++n) {
            const int r = wn * 32 + n * 16 + fr;
            bh[n] = *(const s16x8*)&Bh[r][kg * 8];
            bl[n] = *(const s16x8*)&Bl[r][kg * 8];
        }
#pragma unroll
        for (int m = 0; m < 2; ++m)
#pragma unroll
            for (int n = 0; n < 2; ++n) {
                acc[m][n] = __builtin_amdgcn_mfma_f32_16x16x32_bf16(ah[m], bh[n], acc[m][n], 0, 0, 0);
                acc[m][n] = __builtin_amdgcn_mfma_f32_16x16x32_bf16(ah[m], bl[n], acc[m][n], 0, 0, 0);
                acc[m][n] = __builtin_amdgcn_mfma_f32_16x16x32_bf16(al[m], bh[n], acc[m][n], 0, 0, 0);
            }
    }

    // epilogue: scale, trace, split to hi/lo bf16; mirror off-diag tiles
    float ts = 0.f;
    const int row_l = wm * 32 + (lane >> 4) * 4;
    const int col_l = wn * 32 + fr;
    const bool mir = (tr != tc);
#pragma unroll
    for (int m = 0; m < 2; ++m)
#pragma unroll
        for (int n = 0; n < 2; ++n) {
            const int gr0 = d0 + row_l + m * 16;
            const int gc  = e0 + col_l + n * 16;
            us4 h4, l4;
#pragma unroll
            for (int r = 0; r < 4; ++r) {
                const float e = acc[m][n][r] * inv;
                const unsigned short h = f2b(e);
                const unsigned short l = f2b(e - b2f(h));
                const size_t o = mb + (size_t)(gr0 + r) * DD + gc;
                Eh[o] = h; El[o] = l;
                h4[r] = h; l4[r] = l;
                if (gr0 + r == gc) ts += e;
            }
            if (mir) {
                const size_t o2 = mb + (size_t)gc * DD + gr0;
                *(us4*)&Eh[o2] = h4;
                *(us4*)&El[o2] = l4;
            }
        }
    if (tr == tc) {
        red[t] = ts;
        __syncthreads();
        for (int s2 = 128; s2 > 0; s2 >>= 1) {
            if (t < s2) red[t] += red[t + s2];
            __syncthreads();
        }
        if (t == 0) atomicAdd(&s_out[bb], red[0]);
    }
}

// ---- E = (D/s)^2, 64x64 tile, BK=64, UPPER-TRIANGLE ONLY (640 blocks) ------
// EXACT round-12/14/15-proven body (bit-identical output).
__global__ __launch_bounds__(256, 4)
void sqm_kernel(const unsigned short* __restrict__ Dh, const unsigned short* __restrict__ Dl,
                unsigned short* __restrict__ Eh, unsigned short* __restrict__ El,
                const float* __restrict__ s_in, float* __restrict__ s_out) {
    const int id   = blockIdx.x;          // 640 = 64 batches x 10 tri-tiles
    const int bb   = id & 63;
    const int tile = id >> 6;
    int tr, tc; tri_map(tile, tr, tc);
    const int d0 = tr * 64, e0 = tc * 64;
    const int t    = threadIdx.x;
    const int lane = t & 63, wid = t >> 6;
    const int wm = wid >> 1, wn = wid & 1;
    const int fr = lane & 15, kg = lane >> 4;
    const size_t mb = (size_t)bb * DDSQ;

    __shared__ unsigned short Ah[64][72];   // pitch 72 shorts (144 B)
    __shared__ unsigned short Al[64][72];
    __shared__ unsigned short Bh[64][72];
    __shared__ unsigned short Bl[64][72];
    __shared__ float red[256];

    const f32x4 z4 = {0.f, 0.f, 0.f, 0.f};
    f32x4 acc[2][2];
#pragma unroll
    for (int m = 0; m < 2; ++m)
#pragma unroll
        for (int n = 0; n < 2; ++n) acc[m][n] = z4;

    const float s   = s_in[bb];
    const float inv = 1.f / (s * s);
    const int row = t >> 2, q = t & 3;    // staging map: 64 rows x 4 k-quads

    for (int kb = 0; kb < DD; kb += 64) {
        const size_t ga = mb + (size_t)(d0 + row) * DD + kb + q * 8;
        const size_t gb = mb + (size_t)(e0 + row) * DD + kb + q * 8;
        const int4 rah0 = *(const int4*)&Dh[ga];
        const int4 rah1 = *(const int4*)&Dh[ga + 32];
        const int4 ral0 = *(const int4*)&Dl[ga];
        const int4 ral1 = *(const int4*)&Dl[ga + 32];
        const int4 rbh0 = *(const int4*)&Dh[gb];
        const int4 rbh1 = *(const int4*)&Dh[gb + 32];
        const int4 rbl0 = *(const int4*)&Dl[gb];
        const int4 rbl1 = *(const int4*)&Dl[gb + 32];
        __syncthreads();
        *(int4*)&Ah[row][q * 8]      = rah0;
        *(int4*)&Ah[row][q * 8 + 32] = rah1;
        *(int4*)&Al[row][q * 8]      = ral0;
        *(int4*)&Al[row][q * 8 + 32] = ral1;
        *(int4*)&Bh[row][q * 8]      = rbh0;
        *(int4*)&Bh[row][q * 8 + 32] = rbh1;
        *(int4*)&Bl[row][q * 8]      = rbl0;
        *(int4*)&Bl[row][q * 8 + 32] = rbl1;
        __syncthreads();

#pragma unroll
        for (int h = 0; h < 2; ++h) {
            const int ko = kg * 8 + 32 * h;
            s16x8 ah[2], al[2], bh[2], bl[2];
#pragma unroll
            for (int m = 0; m < 2; ++m) {
                const int r = wm * 32 + m * 16 + fr;
                ah[m] = *(const s16x8*)&Ah[r][ko];
                al[m] = *(const s16x8*)&Al[r][ko];
            }
#pragma unroll
            for (int n = 0; n < 2; ++n) {
                const int r = wn * 32 + n * 16 + fr;
                bh[n] = *(const s16x8*)&Bh[r][ko];
                bl[n] = *(const s16x8*)&Bl[r][ko];
            }
#pragma unroll
            for (int m = 0; m < 2; ++m)
#pragma unroll
                for (int n = 0; n < 2; ++n) {
                    acc[m][n] = __builtin_amdgcn_mfma_f32_16x16x32_bf16(ah[m], bh[n], acc[m][n], 0, 0, 0);
                    acc[m][n] = __builtin_amdgcn_mfma_f32_16x16x32_bf16(ah[m], bl[n], acc[m][n], 0, 0, 0);
                    acc[m][n] = __builtin_amdgcn_mfma_f32_16x16x32_bf16(al[m], bh[n], acc[m][n], 0, 0, 0);
                }
        }
    }

    // epilogue: scale, trace, split to hi/lo bf16; mirror off-diag tiles
    float ts = 0.f;
    const int row_l = wm * 32 + (lane >> 4) * 4;
    const int col_l = wn * 32 + fr;
    const bool mir = (tr != tc);
#pragma unroll
    for (int m = 0; m < 2; ++m)
#pragma unroll
        for (int n = 0; n < 2; ++n) {
            const int gr0 = d0 + row_l + m * 16;
            const int gc  = e0 + col_l + n * 16;
            us4 h4, l4;
#pragma unroll
            for (int r = 0; r < 4; ++r) {
                const float e = acc[m][n][r] * inv;
                const unsigned short h = f2b(e);
                const unsigned short l = f2b(e - b2f(h));
                const size_t o = mb + (size_t)(gr0 + r) * DD + gc;
                Eh[o] = h; El[o] = l;
                h4[r] = h; l4[r] = l;
                if (gr0 + r == gc) ts += e;
            }
            if (mir) {
                const size_t o2 = mb + (size_t)gc * DD + gr0;
                *(us4*)&Eh[o2] = h4;
                *(us4*)&El[o2] = l4;
            }
        }
    if (tr == tc) {
        red[t] = ts;
        __syncthreads();
        for (int s2 = 128; s2 > 0; s2 >>= 1) {
            if (t < s2) red[t] += red[t + s2];
            __syncthreads();
        }
        if (t == 0) atomicAdd(&s_out[bb], red[0]);
    }
}

// ------- finish: 1024 threads/block (round-15 proven) -----------------------
__global__ __launch_bounds__(1024, 1)
void finish_kernel(const unsigned short* __restrict__ Dh,
                   const unsigned short* __restrict__ Dl,
                   float* __restrict__ out) {
    const int b = blockIdx.x, t = threadIdx.x;
    const int row = t >> 2, q = t & 3;
    const size_t mb = (size_t)b * DDSQ;
    __shared__ float vs[DD];
    __shared__ float red[DD];
    __shared__ int   ridx[DD];
    if (t < DD) {
        red[t] = b2f(Dh[mb + (size_t)t * DD + t]) + b2f(Dl[mb + (size_t)t * DD + t]);
        ridx[t] = t;
    }
    __syncthreads();
    for (int s = 128; s > 0; s >>= 1) {
        if (t < s && red[t + s] > red[t]) { red[t] = red[t + s]; ridx[t] = ridx[t + s]; }
        __syncthreads();
    }
    const int jmax0 = ridx[0];
    __syncthreads();
    if (t < DD)
        vs[t] = b2f(Dh[mb + (size_t)jmax0 * DD + t]) + b2f(Dl[mb + (size_t)jmax0 * DD + t]);
    __syncthreads();

    const unsigned short* rh = Dh + mb + (size_t)row * DD + q * 64;
    const unsigned short* rl = Dl + mb + (size_t)row * DD + q * 64;
    for (int it = 0; it < NPI; ++it) {
        float a = 0.f;
        const float* vq = vs + q * 64;
#pragma unroll
        for (int j = 0; j < 64; j += 8) {
            const us8 h8 = *(const us8*)&rh[j];
            const us8 l8 = *(const us8*)&rl[j];
            a = fmaf(b2f(h8[0]) + b2f(l8[0]), vq[j + 0], a);
            a = fmaf(b2f(h8[1]) + b2f(l8[1]), vq[j + 1], a);
            a = fmaf(b2f(h8[2]) + b2f(l8[2]), vq[j + 2], a);
            a = fmaf(b2f(h8[3]) + b2f(l8[3]), vq[j + 3], a);
            a = fmaf(b2f(h8[4]) + b2f(l8[4]), vq[j + 4], a);
            a = fmaf(b2f(h8[5]) + b2f(l8[5]), vq[j + 5], a);
            a = fmaf(b2f(h8[6]) + b2f(l8[6]), vq[j + 6], a);
            a = fmaf(b2f(h8[7]) + b2f(l8[7]), vq[j + 7], a);
        }
        a += __shfl_xor(a, 1);
        a += __shfl_xor(a, 2);
        __syncthreads();
        if (q == 0) vs[row] = a;
        __syncthreads();
    }

    if (t < DD) red[t] = vs[t] * vs[t];
    __syncthreads();
    for (int s = 128; s > 0; s >>= 1) {
        if (t < s) red[t] += red[t + s];
        __syncthreads();
    }
    const float nrm = sqrtf(red[0]);
    __syncthreads();
    if (t < DD) { red[t] = fabsf(vs[t]); ridx[t] = t; }
    __syncthreads();
    for (int s = 128; s > 0; s >>= 1) {
        if (t < s && red[t + s] > red[t]) { red[t] = red[t + s]; ridx[t] = ridx[t + s]; }
        __syncthreads();
    }
    const float sgn = (vs[ridx[0]] < 0.f) ? -1.f : 1.f;
    if (t < DD) out[(size_t)b * DD + t] = sgn * vs[t] / nrm;
}

extern "C" void kernel_launch(void* const* d_in, const int* in_sizes, int n_in,
                              void* d_out, int out_size, void* d_ws, size_t ws_size,
                              hipStream_t stream) {
    const float* caps = (const float*)d_in[0];   // (64, 2048, 16)
    const float* W    = (const float*)d_in[1];   // (2048, 16, 256)
    float* out = (float*)d_out;                  // (64, 256)
    float* ws  = (float*)d_ws;

    // layout: Up packed @0..8PB | F0 fp32 @8PB | F1 fp32 @9PB | Sc @10PB
    // After cm64sk: Up dead -> B0 (chain ping) overlays @0.
    // After sqf:    F0 dead -> B1 (chain pong) overlays @8PB.  168 MB total.
    unsigned* Up = (unsigned*)ws;
    float* F0 = ws + (size_t)8 * PB;
    float* F1 = ws + (size_t)9 * PB;
    float* Sc = ws + (size_t)10 * PB;
    unsigned short* B0h = (unsigned short*)ws;
    unsigned short* B0l = B0h + (size_t)NB * DDSQ;
    unsigned short* B1h = (unsigned short*)(ws + (size_t)8 * PB);
    unsigned short* B1l = B1h + (size_t)NB * DDSQ;

    hipMemsetAsync(Sc, 0, 2048 * sizeof(float), stream);

    u_kernel<<<IC, 256, 0, stream>>>(caps, W, Up);
    cm64sk_kernel<<<1280, 256, 0, stream>>>(Up, F0, F1, Sc);   // C halves (fp32)

    // squaring #1: fold F0+F1 -> bf16 pair B0 (over dead Up region)
    sqf_kernel<<<640, 256, 0, stream>>>(F0, F1, B0h, B0l, Sc, Sc + 64);

    unsigned short* ph = B0h; unsigned short* pl = B0l;
    unsigned short* qh = B1h; unsigned short* ql = B1l;
    for (int it = 1; it < NSQ; ++it) {
        sqm_kernel<<<640, 256, 0, stream>>>(ph, pl, qh, ql,
                                            Sc + it * 64, Sc + (it + 1) * 64);
        unsigned short* t1 = ph; ph = qh; qh = t1;
        unsigned short* t2 = pl; pl = ql; ql = t2;
    }

    finish_kernel<<<NB, 1024, 0, stream>>>(ph, pl, out);   // 10 swaps -> B0
}